// Round 3
// baseline (517.853 us; speedup 1.0000x reference)
//
#include <hip/hip_runtime.h>
#include <hip/hip_bf16.h>
#include <math.h>

using bf16 = __hip_bfloat16;
typedef __bf16 bf16x8v __attribute__((ext_vector_type(8)));
typedef float f32x4v __attribute__((ext_vector_type(4)));

__device__ __forceinline__ float fclamp(float v) {
  // NaN firewall: fmaxf/fminf return the non-NaN operand, so NaN -> -6e4.
  // Correct-path values are |v| <= ~40; never triggers when healthy.
  return fminf(fmaxf(v, -6.0e4f), 6.0e4f);
}

// ---------------------------------------------------------------------------
// fp32 -> bf16 flat conversion, 8 elements/thread.
// ---------------------------------------------------------------------------
__global__ __launch_bounds__(256) void f32_to_bf16(
    const float* __restrict__ in, bf16* __restrict__ out, int n) {
  int i = (blockIdx.x * 256 + threadIdx.x) * 8;
  if (i + 8 > n) return;
  float4 a = *(const float4*)&in[i];
  float4 b = *(const float4*)&in[i + 4];
  alignas(16) bf16 t[8];
  t[0] = __float2bfloat16(a.x); t[1] = __float2bfloat16(a.y);
  t[2] = __float2bfloat16(a.z); t[3] = __float2bfloat16(a.w);
  t[4] = __float2bfloat16(b.x); t[5] = __float2bfloat16(b.y);
  t[6] = __float2bfloat16(b.z); t[7] = __float2bfloat16(b.w);
  *(uint4*)&out[i] = *(const uint4*)t;
}

// ---------------------------------------------------------------------------
// Fused transpose + fp32->bf16: out[c][r] = bf16(in[r][c]), 64x64 tiles.
// ---------------------------------------------------------------------------
__global__ __launch_bounds__(256) void transpose_cvt(
    const float* __restrict__ in, bf16* __restrict__ out, int rows, int cols) {
  __shared__ alignas(16) bf16 tile[64][80];  // 80: keep 16B-aligned rows
  const int t = threadIdx.x;
  const int bx = blockIdx.x * 64;  // input col base
  const int by = blockIdx.y * 64;  // input row base
#pragma unroll
  for (int p = 0; p < 4; ++p) {
    int idx = p * 1024 + t * 4;    // element in 64x64 tile
    int r = idx >> 6, c0 = idx & 63;
    float4 v = *(const float4*)&in[(size_t)(by + r) * cols + bx + c0];
    tile[c0 + 0][r] = __float2bfloat16(v.x);
    tile[c0 + 1][r] = __float2bfloat16(v.y);
    tile[c0 + 2][r] = __float2bfloat16(v.z);
    tile[c0 + 3][r] = __float2bfloat16(v.w);
  }
  __syncthreads();
#pragma unroll
  for (int p = 0; p < 2; ++p) {
    int idx = p * 2048 + t * 8;
    int c = idx >> 6, r0 = idx & 63;
    *(uint4*)&out[(size_t)(bx + c) * rows + by + r0] = *(const uint4*)&tile[c][r0];
  }
}

// ---------------------------------------------------------------------------
// GEMM: C = A[M x 1024](bf16) * W(bf16 Bt=[N][K]) + bias(fp32).
// MODE 0: C[m][n] flat (OutT=float -> d_out)
// MODE 1: head-split   [B,H,S,Dh] (OutT=bf16)
// MODE 2: head-split+T [B,H,Dh,S] (OutT=bf16)
// 128x128 tile, BK=32, 4 waves, 4x4 16x16x32 MFMAs/wave.
// ---------------------------------------------------------------------------
template <typename OutT, int MODE>
__global__ __launch_bounds__(256, 2) void gemm_bt(
    const bf16* __restrict__ A, const bf16* __restrict__ Bt,
    const float* __restrict__ bias, OutT* __restrict__ C, int M) {
  constexpr int K = 1024;
  constexpr int N = 1024;
  __shared__ alignas(16) bf16 As[128 * 32];
  __shared__ alignas(16) bf16 Bs[128 * 32];
  const int t = threadIdx.x;
  const int wave = t >> 6, lane = t & 63;
  const int quad = lane >> 4, l16 = lane & 15;
  const int bm = blockIdx.x * 128, bn = blockIdx.y * 128;
  const int wm = (wave & 1) * 64, wn = (wave >> 1) * 64;

  f32x4v acc[4][4] = {};

  for (int k0 = 0; k0 < K; k0 += 32) {
    uint4 va[2], vb[2];
#pragma unroll
    for (int c = 0; c < 2; ++c) {
      int idx = c * 2048 + t * 8;    // element index in 128x32 tile
      int row = idx >> 5, col = idx & 31;
      va[c] = *(const uint4*)&A[(size_t)(bm + row) * K + k0 + col];
      vb[c] = *(const uint4*)&Bt[(size_t)(bn + row) * K + k0 + col];
    }
    __syncthreads();  // previous iteration's LDS reads complete
#pragma unroll
    for (int c = 0; c < 2; ++c) {
      int idx = c * 2048 + t * 8;
      *(uint4*)&As[idx] = va[c];
      *(uint4*)&Bs[idx] = vb[c];
    }
    __syncthreads();

    bf16x8v a[4], b[4];
#pragma unroll
    for (int mi = 0; mi < 4; ++mi)
      a[mi] = *(const bf16x8v*)&As[(wm + mi * 16 + l16) * 32 + quad * 8];
#pragma unroll
    for (int ni = 0; ni < 4; ++ni)
      b[ni] = *(const bf16x8v*)&Bs[(wn + ni * 16 + l16) * 32 + quad * 8];
#pragma unroll
    for (int mi = 0; mi < 4; ++mi)
#pragma unroll
      for (int ni = 0; ni < 4; ++ni)
        acc[mi][ni] = __builtin_amdgcn_mfma_f32_16x16x32_bf16(a[mi], b[ni],
                                                              acc[mi][ni], 0, 0, 0);
  }

#pragma unroll
  for (int ni = 0; ni < 4; ++ni) {
    int n = bn + wn + ni * 16 + l16;
    float bz = bias[n];
#pragma unroll
    for (int mi = 0; mi < 4; ++mi) {
#pragma unroll
      for (int r = 0; r < 4; ++r) {
        int m = bm + wm + mi * 16 + quad * 4 + r;  // D: row=quad*4+r, col=l16
        float v = fclamp(acc[mi][ni][r] + bz);
        size_t oidx;
        if (MODE == 0) {
          oidx = (size_t)m * N + n;
        } else {
          int b_ = m >> 11, s_ = m & 2047, h_ = n >> 6, d_ = n & 63;
          if (MODE == 1) oidx = ((size_t)(b_ * 16 + h_) * 2048 + s_) * 64 + d_;
          else           oidx = ((size_t)(b_ * 16 + h_) * 64 + d_) * 2048 + s_;
        }
        if constexpr (__is_same(OutT, float)) C[oidx] = v;
        else                                  C[oidx] = __float2bfloat16(v);
      }
    }
  }
}

// ---------------------------------------------------------------------------
// Flash attention: one block = one (b,h) x 128 q-rows; 64-key tiles.
// Qh,Kh: [B,H,S,Dh] bf16; Vt: [B,H,Dh,S] bf16; Ctx: [B,S,H*Dh] bf16.
// Wave owns 32 q-rows. Online softmax in regs (16-lane shfl reductions).
// P round-trips per-wave LDS: C-layout (col=l16,row=quad*4+r) ->
// A-operand layout (A[m=l16][k=quad*8+j]).
// ---------------------------------------------------------------------------
__global__ __launch_bounds__(256, 2) void attn(
    const bf16* __restrict__ Qh, const bf16* __restrict__ Kh,
    const bf16* __restrict__ Vt, bf16* __restrict__ Ctx) {
  __shared__ alignas(16) bf16 Qs[128 * 64];   // 16 KB
  __shared__ alignas(16) bf16 Ks[64 * 64];    // 8 KB  [key][dh]
  __shared__ alignas(16) bf16 Vs[64 * 64];    // 8 KB  [dh][key]
  __shared__ alignas(16) bf16 Ps[4][32 * 64]; // 16 KB per-wave P
  const int t = threadIdx.x;
  const int wave = t >> 6, lane = t & 63;
  const int quad = lane >> 4, l16 = lane & 15;
  const int qb = blockIdx.x;  // 0..15
  const int bh = blockIdx.y;  // 0..31
  const size_t bh_off = (size_t)bh * 2048 * 64;
  const bf16* Qb = Qh + bh_off;
  const bf16* Kb = Kh + bh_off;
  const bf16* Vb = Vt + bh_off;  // [64][2048]

  // stage Q tile [128][64] (cross-wave visible after first in-loop barrier)
#pragma unroll
  for (int c = 0; c < 4; ++c) {
    int idx = c * 2048 + t * 8;
    int row = idx >> 6, col = idx & 63;
    *(uint4*)&Qs[idx] = *(const uint4*)&Qb[(size_t)(qb * 128 + row) * 64 + col];
  }

  const float csc = 0.125f * 1.4426950408889634f;  // 1/sqrt(64) * log2(e)
  float mrow[2][4], lrow[2][4];
#pragma unroll
  for (int mi = 0; mi < 2; ++mi)
#pragma unroll
    for (int r = 0; r < 4; ++r) { mrow[mi][r] = -1.0e30f; lrow[mi][r] = 0.f; }
  f32x4v oacc[2][4] = {};

  for (int kt = 0; kt < 32; ++kt) {  // 64 keys per tile
    uint4 kv[2], vv[2];
#pragma unroll
    for (int c = 0; c < 2; ++c) {
      int idx = c * 2048 + t * 8;
      int row = idx >> 6, col = idx & 63;
      kv[c] = *(const uint4*)&Kb[(size_t)(kt * 64 + row) * 64 + col];
      vv[c] = *(const uint4*)&Vb[(size_t)row * 2048 + kt * 64 + col];
    }
    __syncthreads();  // prev iter's K/V LDS reads done (also fences Q stores)
#pragma unroll
    for (int c = 0; c < 2; ++c) {
      int idx = c * 2048 + t * 8;
      *(uint4*)&Ks[idx] = kv[c];
      *(uint4*)&Vs[idx] = vv[c];
    }
    __syncthreads();

    // S = Q_wave (32x64) x K^T (64x64)
    f32x4v s[2][4] = {};
#pragma unroll
    for (int kk = 0; kk < 2; ++kk) {
      bf16x8v aq[2], bk[4];
#pragma unroll
      for (int mi = 0; mi < 2; ++mi)
        aq[mi] = *(const bf16x8v*)&Qs[(wave * 32 + mi * 16 + l16) * 64 + kk * 32 + quad * 8];
#pragma unroll
      for (int ni = 0; ni < 4; ++ni)
        bk[ni] = *(const bf16x8v*)&Ks[(ni * 16 + l16) * 64 + kk * 32 + quad * 8];
#pragma unroll
      for (int mi = 0; mi < 2; ++mi)
#pragma unroll
        for (int ni = 0; ni < 4; ++ni)
          s[mi][ni] = __builtin_amdgcn_mfma_f32_16x16x32_bf16(aq[mi], bk[ni],
                                                              s[mi][ni], 0, 0, 0);
    }
    // score firewall (healthy |s| <= ~40)
#pragma unroll
    for (int mi = 0; mi < 2; ++mi)
#pragma unroll
      for (int ni = 0; ni < 4; ++ni)
#pragma unroll
        for (int r = 0; r < 4; ++r)
          s[mi][ni][r] = fminf(fmaxf(s[mi][ni][r], -3.0e4f), 3.0e4f);

    // online softmax: row = mi*16 + quad*4 + r, cols across 16 lanes x 4 blocks
#pragma unroll
    for (int mi = 0; mi < 2; ++mi) {
#pragma unroll
      for (int r = 0; r < 4; ++r) {
        float lm = s[mi][0][r];
#pragma unroll
        for (int ni = 1; ni < 4; ++ni) lm = fmaxf(lm, s[mi][ni][r]);
#pragma unroll
        for (int msk = 1; msk < 16; msk <<= 1)
          lm = fmaxf(lm, __shfl_xor(lm, msk, 64));
        float mnew = fmaxf(mrow[mi][r], lm * csc);
        float alpha = exp2f(mrow[mi][r] - mnew);
        mrow[mi][r] = mnew;
#pragma unroll
        for (int ni = 0; ni < 4; ++ni) oacc[mi][ni][r] *= alpha;
        float rs = 0.f;
#pragma unroll
        for (int ni = 0; ni < 4; ++ni) {
          float p = exp2f(s[mi][ni][r] * csc - mnew);
          s[mi][ni][r] = p;
          rs += p;
        }
#pragma unroll
        for (int msk = 1; msk < 16; msk <<= 1) rs += __shfl_xor(rs, msk, 64);
        lrow[mi][r] = lrow[mi][r] * alpha + rs;
      }
    }

    // P (C-layout) -> per-wave LDS
#pragma unroll
    for (int mi = 0; mi < 2; ++mi)
#pragma unroll
      for (int ni = 0; ni < 4; ++ni)
#pragma unroll
        for (int r = 0; r < 4; ++r)
          Ps[wave][(mi * 16 + quad * 4 + r) * 64 + ni * 16 + l16] =
              __float2bfloat16(s[mi][ni][r]);
    __syncthreads();

    // O += P (32x64) x V (64x64); V [dh][key] so B-frag contiguous along k
#pragma unroll
    for (int kk = 0; kk < 2; ++kk) {
      bf16x8v ap[2], bv[4];
#pragma unroll
      for (int mi = 0; mi < 2; ++mi)
        ap[mi] = *(const bf16x8v*)&Ps[wave][(mi * 16 + l16) * 64 + kk * 32 + quad * 8];
#pragma unroll
      for (int ni = 0; ni < 4; ++ni)
        bv[ni] = *(const bf16x8v*)&Vs[(ni * 16 + l16) * 64 + kk * 32 + quad * 8];
#pragma unroll
      for (int mi = 0; mi < 2; ++mi)
#pragma unroll
        for (int ni = 0; ni < 4; ++ni)
          oacc[mi][ni] = __builtin_amdgcn_mfma_f32_16x16x32_bf16(ap[mi], bv[ni],
                                                                 oacc[mi][ni], 0, 0, 0);
    }
  }

  // epilogue: O / l -> Ctx[b][s][h*64+dh]
  const int b_ = bh >> 4, h_ = bh & 15;
#pragma unroll
  for (int mi = 0; mi < 2; ++mi) {
#pragma unroll
    for (int r = 0; r < 4; ++r) {
      int srow = qb * 128 + wave * 32 + mi * 16 + quad * 4 + r;
      float inv = 1.0f / fmaxf(lrow[mi][r], 1.0e-20f);
#pragma unroll
      for (int ni = 0; ni < 4; ++ni) {
        int col = h_ * 64 + ni * 16 + l16;
        Ctx[(size_t)(b_ * 2048 + srow) * 1024 + col] =
            __float2bfloat16(fclamp(oacc[mi][ni][r] * inv));
      }
    }
  }
}

extern "C" void kernel_launch(void* const* d_in, const int* in_sizes, int n_in,
                              void* d_out, int out_size, void* d_ws, size_t ws_size,
                              hipStream_t stream) {
  // Inputs/outputs are fp32 (reference dtype); bf16 is internal only.
  const float* q   = (const float*)d_in[0];
  const float* k   = (const float*)d_in[1];
  const float* v   = (const float*)d_in[2];
  const float* w_q = (const float*)d_in[3];
  const float* b_q = (const float*)d_in[4];
  const float* w_k = (const float*)d_in[5];
  const float* b_k = (const float*)d_in[6];
  const float* w_v = (const float*)d_in[7];
  const float* b_v = (const float*)d_in[8];
  const float* w_o = (const float*)d_in[9];
  const float* b_o = (const float*)d_in[10];
  float* out = (float*)d_out;

  char* ws = (char*)d_ws;
  const size_t MB = (size_t)1024 * 1024;
  bf16* WtQ  = (bf16*)(ws + 0 * MB);   // [N][K] bf16, 2 MiB each
  bf16* WtK  = (bf16*)(ws + 2 * MB);
  bf16* WtV  = (bf16*)(ws + 4 * MB);
  bf16* WtO  = (bf16*)(ws + 6 * MB);
  bf16* Conv = (bf16*)(ws + 8 * MB);   // 8 MiB: q/k/v bf16 (serially reused), then Ctx
  bf16* Qh   = (bf16*)(ws + 16 * MB);  // [2,16,2048,64]
  bf16* Kh   = (bf16*)(ws + 24 * MB);
  bf16* Vt   = (bf16*)(ws + 32 * MB);  // [2,16,64,2048]
  bf16* Ctx  = Conv;                   // attn out [2,2048,1024]; Conv free by then

  const int NACT = 2 * 2048 * 1024;  // activation elements
  dim3 tb(256);
  dim3 gT(16, 16);
  dim3 gC(NACT / (256 * 8));
  dim3 gG(32, 8);

  transpose_cvt<<<gT, tb, 0, stream>>>(w_q, WtQ, 1024, 1024);
  transpose_cvt<<<gT, tb, 0, stream>>>(w_k, WtK, 1024, 1024);
  transpose_cvt<<<gT, tb, 0, stream>>>(w_v, WtV, 1024, 1024);
  transpose_cvt<<<gT, tb, 0, stream>>>(w_o, WtO, 1024, 1024);

  f32_to_bf16<<<gC, tb, 0, stream>>>(q, Conv, NACT);
  gemm_bt<bf16, 1><<<gG, tb, 0, stream>>>(Conv, WtQ, b_q, Qh, 4096);
  f32_to_bf16<<<gC, tb, 0, stream>>>(k, Conv, NACT);
  gemm_bt<bf16, 1><<<gG, tb, 0, stream>>>(Conv, WtK, b_k, Kh, 4096);
  f32_to_bf16<<<gC, tb, 0, stream>>>(v, Conv, NACT);
  gemm_bt<bf16, 2><<<gG, tb, 0, stream>>>(Conv, WtV, b_v, Vt, 4096);

  attn<<<dim3(16, 32), tb, 0, stream>>>(Qh, Kh, Vt, Ctx);

  gemm_bt<float, 0><<<gG, tb, 0, stream>>>(Ctx, WtO, b_o, out, 4096);
}

// Round 4
// 402.409 us; speedup vs baseline: 1.2869x; 1.2869x over previous
//
#include <hip/hip_runtime.h>
#include <hip/hip_bf16.h>
#include <math.h>

using bf16 = __hip_bfloat16;
typedef __bf16 bf16x8v __attribute__((ext_vector_type(8)));
typedef float f32x4v __attribute__((ext_vector_type(4)));

__device__ __forceinline__ float fclamp(float v) {
  return fminf(fmaxf(v, -6.0e4f), 6.0e4f);  // NaN firewall; never hit when healthy
}

// DPP cross-lane move within 16-lane rows (VALU pipe, not LDS pipe).
template <int CTRL>
__device__ __forceinline__ float dpp_f(float x) {
  return __int_as_float(
      __builtin_amdgcn_update_dpp(0, __float_as_int(x), CTRL, 0xF, 0xF, true));
}
// Reduce across the 16 lanes of a DPP row (our quad-group of l16 lanes).
__device__ __forceinline__ float red_max16(float x) {
  x = fmaxf(x, dpp_f<0xB1>(x));    // quad_perm(1,0,3,2): xor 1
  x = fmaxf(x, dpp_f<0x4E>(x));    // quad_perm(2,3,0,1): xor 2
  x = fmaxf(x, dpp_f<0x124>(x));   // row_ror:4
  x = fmaxf(x, dpp_f<0x128>(x));   // row_ror:8
  return x;
}
__device__ __forceinline__ float red_add16(float x) {
  x += dpp_f<0xB1>(x);
  x += dpp_f<0x4E>(x);
  x += dpp_f<0x124>(x);
  x += dpp_f<0x128>(x);
  return x;
}

// ---------------------------------------------------------------------------
// Fused transpose + fp32->bf16 for all 4 weights: out[c][r] = bf16(in[r][c]).
// ---------------------------------------------------------------------------
__global__ __launch_bounds__(256) void transpose_cvt4(
    const float* __restrict__ w0, const float* __restrict__ w1,
    const float* __restrict__ w2, const float* __restrict__ w3,
    bf16* __restrict__ o0, bf16* __restrict__ o1,
    bf16* __restrict__ o2, bf16* __restrict__ o3) {
  const float* in = (blockIdx.z == 0) ? w0 : (blockIdx.z == 1) ? w1
                    : (blockIdx.z == 2) ? w2 : w3;
  bf16* out = (blockIdx.z == 0) ? o0 : (blockIdx.z == 1) ? o1
              : (blockIdx.z == 2) ? o2 : o3;
  __shared__ alignas(16) bf16 tile[64][80];
  const int t = threadIdx.x;
  const int bx = blockIdx.x * 64, by = blockIdx.y * 64;
#pragma unroll
  for (int p = 0; p < 4; ++p) {
    int idx = p * 1024 + t * 4;
    int r = idx >> 6, c0 = idx & 63;
    float4 v = *(const float4*)&in[(size_t)(by + r) * 1024 + bx + c0];
    tile[c0 + 0][r] = __float2bfloat16(v.x);
    tile[c0 + 1][r] = __float2bfloat16(v.y);
    tile[c0 + 2][r] = __float2bfloat16(v.z);
    tile[c0 + 3][r] = __float2bfloat16(v.w);
  }
  __syncthreads();
#pragma unroll
  for (int p = 0; p < 2; ++p) {
    int idx = p * 2048 + t * 8;
    int c = idx >> 6, r0 = idx & 63;
    *(uint4*)&out[(size_t)(bx + c) * 1024 + by + r0] = *(const uint4*)&tile[c][r0];
  }
}

// ---------------------------------------------------------------------------
// Fused Q/K/V projection GEMM. blockIdx.z selects tensor. A is fp32 (cvt
// inline during staging). Bt = W^T [N][K] bf16. 128x128 tile, BK=32, 4 waves.
// LDS row stride 40 (pad +8) to break 8-way bank conflicts.
// z=0,1 -> head-split [B,H,S,Dh]; z=2 -> head-split-T [B,H,Dh,S].
// ---------------------------------------------------------------------------
__global__ __launch_bounds__(256, 3) void gemm_qkv(
    const float* __restrict__ Aq, const float* __restrict__ Ak,
    const float* __restrict__ Av,
    const bf16* __restrict__ WtQ, const bf16* __restrict__ WtK,
    const bf16* __restrict__ WtV,
    const float* __restrict__ bq, const float* __restrict__ bk_,
    const float* __restrict__ bv_,
    bf16* __restrict__ Qh, bf16* __restrict__ Kh, bf16* __restrict__ Vt) {
  constexpr int K = 1024, LDA = 40;
  const int z = blockIdx.z;
  const float* A  = (z == 0) ? Aq : (z == 1) ? Ak : Av;
  const bf16* Bt  = (z == 0) ? WtQ : (z == 1) ? WtK : WtV;
  const float* bias = (z == 0) ? bq : (z == 1) ? bk_ : bv_;
  bf16* C = (z == 0) ? Qh : (z == 1) ? Kh : Vt;

  __shared__ alignas(16) bf16 As[128 * LDA];
  __shared__ alignas(16) bf16 Bs[128 * LDA];
  const int t = threadIdx.x;
  const int wave = t >> 6, lane = t & 63;
  const int quad = lane >> 4, l16 = lane & 15;
  const int bm = blockIdx.x * 128, bn = blockIdx.y * 128;
  const int wm = (wave & 1) * 64, wn = (wave >> 1) * 64;

  f32x4v acc[4][4] = {};

  for (int k0 = 0; k0 < K; k0 += 32) {
    uint4 va[2], vb[2];
#pragma unroll
    for (int c = 0; c < 2; ++c) {
      int idx = c * 2048 + t * 8;
      int row = idx >> 5, col = idx & 31;
      const float* src = &A[(size_t)(bm + row) * K + k0 + col];
      float4 f0 = *(const float4*)src;
      float4 f1 = *(const float4*)(src + 4);
      alignas(16) bf16 tmp[8];
      tmp[0] = __float2bfloat16(f0.x); tmp[1] = __float2bfloat16(f0.y);
      tmp[2] = __float2bfloat16(f0.z); tmp[3] = __float2bfloat16(f0.w);
      tmp[4] = __float2bfloat16(f1.x); tmp[5] = __float2bfloat16(f1.y);
      tmp[6] = __float2bfloat16(f1.z); tmp[7] = __float2bfloat16(f1.w);
      va[c] = *(const uint4*)tmp;
      vb[c] = *(const uint4*)&Bt[(size_t)(bn + row) * K + k0 + col];
    }
    __syncthreads();
#pragma unroll
    for (int c = 0; c < 2; ++c) {
      int idx = c * 2048 + t * 8;
      int row = idx >> 5, col = idx & 31;
      *(uint4*)&As[row * LDA + col] = va[c];
      *(uint4*)&Bs[row * LDA + col] = vb[c];
    }
    __syncthreads();

    bf16x8v a[4], b[4];
#pragma unroll
    for (int mi = 0; mi < 4; ++mi)
      a[mi] = *(const bf16x8v*)&As[(wm + mi * 16 + l16) * LDA + quad * 8];
#pragma unroll
    for (int ni = 0; ni < 4; ++ni)
      b[ni] = *(const bf16x8v*)&Bs[(wn + ni * 16 + l16) * LDA + quad * 8];
#pragma unroll
    for (int mi = 0; mi < 4; ++mi)
#pragma unroll
      for (int ni = 0; ni < 4; ++ni)
        acc[mi][ni] = __builtin_amdgcn_mfma_f32_16x16x32_bf16(a[mi], b[ni],
                                                              acc[mi][ni], 0, 0, 0);
  }

#pragma unroll
  for (int ni = 0; ni < 4; ++ni) {
    int n = bn + wn + ni * 16 + l16;
    float bz = bias[n];
#pragma unroll
    for (int mi = 0; mi < 4; ++mi) {
#pragma unroll
      for (int r = 0; r < 4; ++r) {
        int m = bm + wm + mi * 16 + quad * 4 + r;  // D: row=quad*4+r, col=l16
        float v = fclamp(acc[mi][ni][r] + bz);
        int b_ = m >> 11, s_ = m & 2047, h_ = n >> 6, d_ = n & 63;
        size_t oidx = (z == 2)
            ? ((size_t)(b_ * 16 + h_) * 64 + d_) * 2048 + s_
            : ((size_t)(b_ * 16 + h_) * 2048 + s_) * 64 + d_;
        C[oidx] = __float2bfloat16(v);
      }
    }
  }
}

// ---------------------------------------------------------------------------
// Output projection: out = Ctx(bf16) @ WtO^T + b_o, fp32 out. 128x64 tile,
// BK=32, 4 waves as 2x2 (wave tile 64x32), grid (32,16)=512 blocks.
// ---------------------------------------------------------------------------
__global__ __launch_bounds__(256, 3) void gemm_out(
    const bf16* __restrict__ A, const bf16* __restrict__ Bt,
    const float* __restrict__ bias, float* __restrict__ C) {
  constexpr int K = 1024, N = 1024, LDA = 40;
  __shared__ alignas(16) bf16 As[128 * LDA];
  __shared__ alignas(16) bf16 Bs[64 * LDA];
  const int t = threadIdx.x;
  const int wave = t >> 6, lane = t & 63;
  const int quad = lane >> 4, l16 = lane & 15;
  const int bm = blockIdx.x * 128, bn = blockIdx.y * 64;
  const int wm = (wave & 1) * 64, wn = (wave >> 1) * 32;

  f32x4v acc[4][2] = {};

  for (int k0 = 0; k0 < K; k0 += 32) {
    uint4 va[2], vb;
#pragma unroll
    for (int c = 0; c < 2; ++c) {
      int idx = c * 2048 + t * 8;
      int row = idx >> 5, col = idx & 31;
      va[c] = *(const uint4*)&A[(size_t)(bm + row) * K + k0 + col];
    }
    {
      int idx = t * 8;
      int row = idx >> 5, col = idx & 31;
      vb = *(const uint4*)&Bt[(size_t)(bn + row) * K + k0 + col];
    }
    __syncthreads();
#pragma unroll
    for (int c = 0; c < 2; ++c) {
      int idx = c * 2048 + t * 8;
      int row = idx >> 5, col = idx & 31;
      *(uint4*)&As[row * LDA + col] = va[c];
    }
    {
      int idx = t * 8;
      int row = idx >> 5, col = idx & 31;
      *(uint4*)&Bs[row * LDA + col] = vb;
    }
    __syncthreads();

    bf16x8v a[4], b[2];
#pragma unroll
    for (int mi = 0; mi < 4; ++mi)
      a[mi] = *(const bf16x8v*)&As[(wm + mi * 16 + l16) * LDA + quad * 8];
#pragma unroll
    for (int ni = 0; ni < 2; ++ni)
      b[ni] = *(const bf16x8v*)&Bs[(wn + ni * 16 + l16) * LDA + quad * 8];
#pragma unroll
    for (int mi = 0; mi < 4; ++mi)
#pragma unroll
      for (int ni = 0; ni < 2; ++ni)
        acc[mi][ni] = __builtin_amdgcn_mfma_f32_16x16x32_bf16(a[mi], b[ni],
                                                              acc[mi][ni], 0, 0, 0);
  }

#pragma unroll
  for (int ni = 0; ni < 2; ++ni) {
    int n = bn + wn + ni * 16 + l16;
    float bz = bias[n];
#pragma unroll
    for (int mi = 0; mi < 4; ++mi)
#pragma unroll
      for (int r = 0; r < 4; ++r) {
        int m = bm + wm + mi * 16 + quad * 4 + r;
        C[(size_t)m * N + n] = fclamp(acc[mi][ni][r] + bz);
      }
  }
}

// ---------------------------------------------------------------------------
// Flash attention. Block = (b,h) x 64 q-rows; wave owns 16 q-rows; 64-key
// tiles. LDS rows padded to 72 (144 B) -> <=2-way bank aliasing (free).
// Softmax reductions via DPP (VALU pipe). Grid (32,32)=1024 blocks, 36 KB
// LDS -> 4 blocks/CU.
// ---------------------------------------------------------------------------
__global__ __launch_bounds__(256, 4) void attn(
    const bf16* __restrict__ Qh, const bf16* __restrict__ Kh,
    const bf16* __restrict__ Vt, bf16* __restrict__ Ctx) {
  constexpr int LDP = 72;
  __shared__ alignas(16) bf16 Qs[64 * LDP];
  __shared__ alignas(16) bf16 Ks[64 * LDP];
  __shared__ alignas(16) bf16 Vs[64 * LDP];
  __shared__ alignas(16) bf16 Ps[4][16 * LDP];
  const int t = threadIdx.x;
  const int wave = t >> 6, lane = t & 63;
  const int quad = lane >> 4, l16 = lane & 15;
  const int qb = blockIdx.x;  // 0..31 (64-row q tiles)
  const int bh = blockIdx.y;  // 0..31
  const size_t bh_off = (size_t)bh * 2048 * 64;
  const bf16* Qb = Qh + bh_off;
  const bf16* Kb = Kh + bh_off;
  const bf16* Vb = Vt + bh_off;  // [64][2048]

  // stage Q tile 64x64 (visible to all waves after first in-loop barrier)
#pragma unroll
  for (int c = 0; c < 2; ++c) {
    int idx = c * 2048 + t * 8;
    int row = idx >> 6, col = idx & 63;
    *(uint4*)&Qs[row * LDP + col] =
        *(const uint4*)&Qb[(size_t)(qb * 64 + row) * 64 + col];
  }

  const float csc = 0.125f * 1.4426950408889634f;  // 1/sqrt(64) * log2(e)
  float mrow[4], lrow[4];
#pragma unroll
  for (int r = 0; r < 4; ++r) { mrow[r] = -1.0e30f; lrow[r] = 0.f; }
  f32x4v oacc[4] = {};

  for (int kt = 0; kt < 32; ++kt) {
    uint4 kv[2], vv[2];
#pragma unroll
    for (int c = 0; c < 2; ++c) {
      int idx = c * 2048 + t * 8;
      int row = idx >> 6, col = idx & 63;
      kv[c] = *(const uint4*)&Kb[(size_t)(kt * 64 + row) * 64 + col];
      vv[c] = *(const uint4*)&Vb[(size_t)row * 2048 + kt * 64 + col];
    }
    __syncthreads();  // prior iteration's LDS reads complete
#pragma unroll
    for (int c = 0; c < 2; ++c) {
      int idx = c * 2048 + t * 8;
      int row = idx >> 6, col = idx & 63;
      *(uint4*)&Ks[row * LDP + col] = kv[c];
      *(uint4*)&Vs[row * LDP + col] = vv[c];
    }
    __syncthreads();

    // S = Q_wave(16x64) x K^T(64x64)
    f32x4v s[4] = {};
#pragma unroll
    for (int kk = 0; kk < 2; ++kk) {
      bf16x8v aq = *(const bf16x8v*)&Qs[(wave * 16 + l16) * LDP + kk * 32 + quad * 8];
      bf16x8v bk[4];
#pragma unroll
      for (int ni = 0; ni < 4; ++ni)
        bk[ni] = *(const bf16x8v*)&Ks[(ni * 16 + l16) * LDP + kk * 32 + quad * 8];
#pragma unroll
      for (int ni = 0; ni < 4; ++ni)
        s[ni] = __builtin_amdgcn_mfma_f32_16x16x32_bf16(aq, bk[ni], s[ni], 0, 0, 0);
    }

    // online softmax; row = quad*4+r, cols across 16 lanes x 4 ni-blocks
#pragma unroll
    for (int r = 0; r < 4; ++r) {
      float lm = fmaxf(fmaxf(s[0][r], s[1][r]), fmaxf(s[2][r], s[3][r]));
      lm = red_max16(lm);
      float mnew = fmaxf(mrow[r], lm * csc);
      float alpha = exp2f(mrow[r] - mnew);
      mrow[r] = mnew;
      float rs = 0.f;
#pragma unroll
      for (int ni = 0; ni < 4; ++ni) {
        float p = exp2f(s[ni][r] * csc - mnew);
        s[ni][r] = p;
        rs += p;
      }
      rs = red_add16(rs);
      lrow[r] = lrow[r] * alpha + rs;
#pragma unroll
      for (int ni = 0; ni < 4; ++ni) oacc[ni][r] *= alpha;
    }

    // P (C-layout) -> per-wave LDS (A-operand layout source)
#pragma unroll
    for (int ni = 0; ni < 4; ++ni)
#pragma unroll
      for (int r = 0; r < 4; ++r)
        Ps[wave][(quad * 4 + r) * LDP + ni * 16 + l16] = __float2bfloat16(s[ni][r]);
    __syncthreads();

    // O += P(16x64) x V(64x64); Vs[dh][key] -> B-frag contiguous along k
#pragma unroll
    for (int kk = 0; kk < 2; ++kk) {
      bf16x8v ap = *(const bf16x8v*)&Ps[wave][l16 * LDP + kk * 32 + quad * 8];
      bf16x8v bv[4];
#pragma unroll
      for (int ni = 0; ni < 4; ++ni)
        bv[ni] = *(const bf16x8v*)&Vs[(ni * 16 + l16) * LDP + kk * 32 + quad * 8];
#pragma unroll
      for (int ni = 0; ni < 4; ++ni)
        oacc[ni] = __builtin_amdgcn_mfma_f32_16x16x32_bf16(ap, bv[ni], oacc[ni], 0, 0, 0);
    }
  }

  // epilogue: O / l -> Ctx[b][s][h*64+dh]
  const int b_ = bh >> 4, h_ = bh & 15;
#pragma unroll
  for (int r = 0; r < 4; ++r) {
    int srow = qb * 64 + wave * 16 + quad * 4 + r;
    float inv = 1.0f / fmaxf(lrow[r], 1.0e-20f);
#pragma unroll
    for (int ni = 0; ni < 4; ++ni) {
      int col = h_ * 64 + ni * 16 + l16;
      Ctx[(size_t)(b_ * 2048 + srow) * 1024 + col] =
          __float2bfloat16(fclamp(oacc[ni][r] * inv));
    }
  }
}

extern "C" void kernel_launch(void* const* d_in, const int* in_sizes, int n_in,
                              void* d_out, int out_size, void* d_ws, size_t ws_size,
                              hipStream_t stream) {
  const float* q   = (const float*)d_in[0];
  const float* k   = (const float*)d_in[1];
  const float* v   = (const float*)d_in[2];
  const float* w_q = (const float*)d_in[3];
  const float* b_q = (const float*)d_in[4];
  const float* w_k = (const float*)d_in[5];
  const float* b_k = (const float*)d_in[6];
  const float* w_v = (const float*)d_in[7];
  const float* b_v = (const float*)d_in[8];
  const float* w_o = (const float*)d_in[9];
  const float* b_o = (const float*)d_in[10];
  float* out = (float*)d_out;

  char* ws = (char*)d_ws;
  const size_t MB = (size_t)1024 * 1024;
  bf16* WtQ = (bf16*)(ws + 0 * MB);
  bf16* WtK = (bf16*)(ws + 2 * MB);
  bf16* WtV = (bf16*)(ws + 4 * MB);
  bf16* WtO = (bf16*)(ws + 6 * MB);
  bf16* Qh  = (bf16*)(ws + 8 * MB);   // [2,16,2048,64]
  bf16* Kh  = (bf16*)(ws + 16 * MB);
  bf16* Vt  = (bf16*)(ws + 24 * MB);  // [2,16,64,2048]
  bf16* Ctx = (bf16*)(ws + 32 * MB);  // [2,2048,1024]

  dim3 tb(256);
  transpose_cvt4<<<dim3(16, 16, 4), tb, 0, stream>>>(w_q, w_k, w_v, w_o,
                                                     WtQ, WtK, WtV, WtO);
  gemm_qkv<<<dim3(32, 8, 3), tb, 0, stream>>>(q, k, v, WtQ, WtK, WtV,
                                              b_q, b_k, b_v, Qh, Kh, Vt);
  attn<<<dim3(32, 32), tb, 0, stream>>>(Qh, Kh, Vt, Ctx);
  gemm_out<<<dim3(32, 16), tb, 0, stream>>>(Ctx, WtO, b_o, out);
}